// Round 19
// baseline (52.631 us; speedup 1.0000x reference)
//
#include <hip/hip_runtime.h>
#include <hip/hip_bf16.h>

typedef float f32x4 __attribute__((ext_vector_type(4)));
typedef float f32x16 __attribute__((ext_vector_type(16)));
typedef __bf16 bf16x8 __attribute__((ext_vector_type(8)));
typedef unsigned int uint2v __attribute__((ext_vector_type(2)));

#define MFMA16(a, b, c) __builtin_amdgcn_mfma_f32_16x16x32_bf16((a), (b), (c), 0, 0, 0)
#define MFMA32(a, b, c) __builtin_amdgcn_mfma_f32_32x32x16_bf16((a), (b), (c), 0, 0, 0)

static __device__ __forceinline__ short f2s(float f) {
    __hip_bfloat16 h = __float2bfloat16(f);
    return *reinterpret_cast<short*>(&h);
}
static __device__ __forceinline__ unsigned int cvtpk(float lo, float hi) {
    unsigned int r;
    asm("v_cvt_pk_bf16_f32 %0, %1, %2" : "=v"(r) : "v"(lo), "v"(hi));
    return r;
}
static __device__ __forceinline__ float exp2f_fast(float x) {
#if __has_builtin(__builtin_amdgcn_exp2f)
    return __builtin_amdgcn_exp2f(x);
#else
    return exp2f(x);
#endif
}

// ---------------------------------------------------------------------------
// Kernel A (fused front): blocks [0,256) = QKV projection with 3-matrix
// A-tile reuse; blocks [256,1280) = adj gather.  Verbatim round 18 (verified).
// ---------------------------------------------------------------------------
__global__ __launch_bounds__(256)
void qkv3_and_gather(const float* __restrict__ x,
                     const float* __restrict__ Wq, const float* __restrict__ bq,
                     const float* __restrict__ Wk, const float* __restrict__ bk,
                     const float* __restrict__ Wv, const float* __restrict__ bv,
                     short* __restrict__ Qb, short* __restrict__ Kb, short* __restrict__ Vb,
                     const int* __restrict__ adj, unsigned int* __restrict__ adjG)
{
    __shared__ short As[128 * 72];
    __shared__ short Bs[3][64 * 72];

    const int bx = blockIdx.x;
    const int tid = threadIdx.x;

    if (bx < 256) {
        const int lane = tid & 63;
        const int wid = tid >> 6;
        const int wr = wid >> 1, wc = wid & 1;
        const int g = lane >> 4, li = lane & 15;

        const int m0 = (bx & 63) * 128;
        const int wc0 = (bx >> 6) * 64;

        const float* Wm[3]  = { Wq, Wk, Wv };
        const float* bm[3]  = { bq, bk, bv };
        short*       Om[3]  = { Qb, Kb, Vb };

        f32x4 acc[3][4][2] = {};

        const int sr = tid >> 4;
        const int sc4 = (tid & 15) * 4;

        for (int k0 = 0; k0 < 256; k0 += 64) {
            __syncthreads();
#pragma unroll
            for (int it = 0; it < 8; ++it) {
                int row = sr + it * 16;
                float4 v = *reinterpret_cast<const float4*>(&x[(m0 + row) * 256 + k0 + sc4]);
                short4 s4;
                s4.x = f2s(v.x); s4.y = f2s(v.y); s4.z = f2s(v.z); s4.w = f2s(v.w);
                *reinterpret_cast<short4*>(&As[row * 72 + sc4]) = s4;
            }
#pragma unroll
            for (int mat = 0; mat < 3; ++mat) {
#pragma unroll
                for (int it = 0; it < 4; ++it) {
                    int row = sr + it * 16;
                    float4 v = *reinterpret_cast<const float4*>(
                        &Wm[mat][(wc0 + row) * 256 + k0 + sc4]);
                    short4 s4;
                    s4.x = f2s(v.x); s4.y = f2s(v.y); s4.z = f2s(v.z); s4.w = f2s(v.w);
                    *reinterpret_cast<short4*>(&Bs[mat][row * 72 + sc4]) = s4;
                }
            }
            __syncthreads();
#pragma unroll
            for (int ks = 0; ks < 2; ++ks) {
                const int kb = ks * 32 + g * 8;
                bf16x8 a[4];
#pragma unroll
                for (int i = 0; i < 4; ++i)
                    a[i] = *reinterpret_cast<const bf16x8*>(&As[(wr * 64 + i * 16 + li) * 72 + kb]);
#pragma unroll
                for (int mat = 0; mat < 3; ++mat) {
                    bf16x8 bfr[2];
#pragma unroll
                    for (int j = 0; j < 2; ++j)
                        bfr[j] = *reinterpret_cast<const bf16x8*>(
                            &Bs[mat][(wc * 32 + j * 16 + li) * 72 + kb]);
#pragma unroll
                    for (int i = 0; i < 4; ++i)
#pragma unroll
                        for (int j = 0; j < 2; ++j)
                            acc[mat][i][j] = MFMA16(a[i], bfr[j], acc[mat][i][j]);
                }
            }
        }

#pragma unroll
        for (int mat = 0; mat < 3; ++mat) {
#pragma unroll
            for (int j = 0; j < 2; ++j) {
                const int colW = wc0 + wc * 32 + j * 16 + li;
                const int h = colW >> 5, d = colW & 31;
                const float bv_ = bm[mat][colW];
#pragma unroll
                for (int i = 0; i < 4; ++i) {
#pragma unroll
                    for (int r = 0; r < 4; ++r) {
                        const int row = m0 + wr * 64 + i * 16 + g * 4 + r;
                        const int bb = row >> 10, nq = row & 1023;
                        Om[mat][((bb * 8 + h) * 1024 + nq) * 32 + d] =
                            f2s(acc[mat][i][j][r] + bv_);
                    }
                }
            }
        }
    } else {
        const int gx = bx - 256;               // 0..1023
        const int qt = gx & 31;
        const int b  = (gx >> 5) & 7;
        const int j0 = (gx >> 8) * 8;

        const int4* base = reinterpret_cast<const int4*>(
            adj + ((size_t)(b * 1024 + qt * 32)) * 1024);
        unsigned int* outT = adjG + ((size_t)(b * 32 + qt)) * 16 * 512;

        const int t = tid >> 4;
        const int i = (tid >> 1) & 7;
        const int laneb = 32 * (tid & 1);

#pragma unroll
        for (int jj = 0; jj < 8; ++jj) {
            const int j = j0 + jj;
            const int4 c = base[j * 256 + tid];
            const unsigned int packed =
                (unsigned)c.x | ((unsigned)c.y << 8) | ((unsigned)c.z << 16) | ((unsigned)c.w << 24);
            outT[t * 512 + i * 64 + (j + laneb)] = packed;
        }
    }
}

// ---------------------------------------------------------------------------
// Kernel B: edge-biased flash attention — k-half split for 2x occupancy.
// Grid (16,64) = 1024 blocks (4/CU -> 16 waves/CU); block = 4 waves =
// 2 q-tiles x 2 k-halves.  Wave (qw,kh) computes q-tile qb*2+qw over k-tiles
// [kh*8, kh*8+8).  Per iteration block stages 2 tiles (t and 8+t); each wave
// computes ONE tile (half the per-wave serial work of attn11).  Fixed-max
// softmax makes the k-half merge a plain add (epilogue via LDS over retired
// K buffers).  All math/staging/swizzle verbatim from verified attn11.
// ---------------------------------------------------------------------------
__global__ __launch_bounds__(256, 4)
void attn12(const short* __restrict__ Qb, const short* __restrict__ Kb,
            const short* __restrict__ Vb, const unsigned int* __restrict__ adjG,
            const float* __restrict__ edge_emb, short* __restrict__ AO)
{
    __shared__ __align__(16) short Ks[4][64 * 36];   // [buf][row][d]
    __shared__ __align__(16) short Vt[4][32 * 72];   // [buf][d][krow] swizzled
    __shared__ float Etab[8];

    const int tid = threadIdx.x, lane = tid & 63, wid = tid >> 6;
    const int l5 = lane & 31, h32 = lane >> 5;
    const int qw = wid & 1, kh = wid >> 1;

    // bijective chunked XCD swizzle (1024 blocks = 8 XCD x 128)
    const int orig = blockIdx.x + blockIdx.y * 16;
    const int flat = (orig & 7) * 128 + (orig >> 3);
    const int qb = flat & 15, bh = flat >> 4;
    const int b = bh >> 3, h = bh & 7;
    const int qt = qb * 2 + qw;          // wave's q-tile (0..31)
    const int q  = qt * 32 + l5;

    const short* Qh = Qb + bh * (1024 * 32);
    const short* Kh = Kb + bh * (1024 * 32);
    const short* Vh = Vb + bh * (1024 * 32);
    const unsigned int* adjT = adjG + ((size_t)(b * 32 + qt)) * 16 * 512;

    if (tid < 5) Etab[tid] = __expf(edge_emb[tid * 8 + h]);

    // Q fragments (B-operand): col=q=l5, k(d) = c*16 + h32*8 + j
    const bf16x8 qf0 = *reinterpret_cast<const bf16x8*>(&Qh[q * 32 + h32 * 8]);
    const bf16x8 qf1 = *reinterpret_cast<const bf16x8*>(&Qh[q * 32 + 16 + h32 * 8]);

    const float c1 = 0.25503486f;   // log2(e)/sqrt(32)
    const f32x16 zero16 = {};

    f32x16 o = {};
    float lr = 0.f;

    // staging map: thread -> (k-row sr = tid>>2, 16B chunk sc = (tid&3)*8)
    const int sr = tid >> 2;
    const int sc = (tid & 3) * 8;
    const int srh = sr >> 3, srl = sr & 7;     // V-swizzle components
    const int scg2 = (sc >> 3) << 1;

    // prologue: stage tile 0 (half 0) and tile 8 (half 1) into buffers 0,1
#pragma unroll
    for (int u = 0; u < 2; ++u) {
        const int row = u * 512 + sr;
        int4 kr = *reinterpret_cast<const int4*>(&Kh[row * 32 + sc]);
        int4 vr = *reinterpret_cast<const int4*>(&Vh[row * 32 + sc]);
        short* kd = &Ks[u][sr * 36 + sc];
        *reinterpret_cast<short4*>(kd)     = *reinterpret_cast<short4*>(&kr);
        *reinterpret_cast<short4*>(kd + 4) = *(reinterpret_cast<short4*>(&kr) + 1);
        const short* vs = reinterpret_cast<const short*>(&vr);
#pragma unroll
        for (int i = 0; i < 8; ++i) {
            const int swz = srh ^ i ^ scg2;
            Vt[u][(sc + i) * 72 + swz * 8 + srl] = vs[i];
        }
    }
    __syncthreads();

    for (int t = 0; t < 8; ++t) {
        const int cur = (t & 1) * 2;
        const int tt = kh * 8 + t;           // this wave's compute tile

        // ---- adj loads for this wave's tile ----
        unsigned int a4[8];
#pragma unroll
        for (int i = 0; i < 8; ++i)
            a4[i] = adjT[tt * 512 + i * 64 + lane];

        // ---- issue next-pair K/V global loads (both halves) ----
        int4 kn[2], vn[2];
        if (t < 7) {
#pragma unroll
            for (int u = 0; u < 2; ++u) {
                const int row = u * 512 + (t + 1) * 64 + sr;
                kn[u] = *reinterpret_cast<const int4*>(&Kh[row * 32 + sc]);
                vn[u] = *reinterpret_cast<const int4*>(&Vh[row * 32 + sc]);
            }
        }

        // ---- QK^T from this wave's buffer ----
        f32x16 s[2];
        {
            const short* KsC = &Ks[cur + kh][0];
#pragma unroll
            for (int ks = 0; ks < 2; ++ks) {
                union { short4 h4[2]; bf16x8 v; } kfa, kfb;
                const int rowb = (ks * 32 + l5) * 36;
                kfa.h4[0] = *reinterpret_cast<const short4*>(&KsC[rowb + h32 * 8]);
                kfa.h4[1] = *reinterpret_cast<const short4*>(&KsC[rowb + h32 * 8 + 4]);
                kfb.h4[0] = *reinterpret_cast<const short4*>(&KsC[rowb + 16 + h32 * 8]);
                kfb.h4[1] = *reinterpret_cast<const short4*>(&KsC[rowb + 16 + h32 * 8 + 4]);
                s[ks] = MFMA32(kfa.v, qf0, zero16);
                s[ks] = MFMA32(kfb.v, qf1, s[ks]);
            }
        }

        // ---- fixed-max softmax: p = exp2(s*c1) * E[adj]; pack bf16 ----
        unsigned int pw[2][8];
#pragma unroll
        for (int ks = 0; ks < 2; ++ks) {
#pragma unroll
            for (int rg = 0; rg < 4; ++rg) {
                const unsigned int aw4 = a4[ks * 4 + rg] << 2;
                float pv[4];
#pragma unroll
                for (int j = 0; j < 4; ++j) {
                    const float Ev = *reinterpret_cast<const float*>(
                        reinterpret_cast<const char*>(&Etab[0]) +
                        ((aw4 >> (8 * j)) & 0x3FCu));
                    const float pe = exp2f_fast(s[ks][rg * 4 + j] * c1);
                    const float pp = pe * Ev;
                    pv[j] = pp;
                    lr += pp;
                }
                pw[ks][rg * 2 + 0] = cvtpk(pv[0], pv[1]);
                pw[ks][rg * 2 + 1] = cvtpk(pv[2], pv[3]);
            }
        }

        // ---- PV: O^T += V^T . P^T ----
#pragma unroll
        for (int kc = 0; kc < 4; ++kc) {
            const int ks = kc >> 1, half = kc & 1;
            const unsigned int A0 = pw[ks][4 * half + 0], A1 = pw[ks][4 * half + 1];
            const unsigned int B0 = pw[ks][4 * half + 2], B1 = pw[ks][4 * half + 3];
            union { unsigned int u[4]; bf16x8 v; } P;
#if __has_builtin(__builtin_amdgcn_permlane32_swap)
            uint2v r02 = __builtin_amdgcn_permlane32_swap(A0, B0, false, false);
            uint2v r13 = __builtin_amdgcn_permlane32_swap(A1, B1, false, false);
            P.u[0] = r02.x; P.u[1] = r13.x;
            P.u[2] = r02.y; P.u[3] = r13.y;
#else
            const unsigned int send0 = h32 ? A0 : B0, send1 = h32 ? A1 : B1;
            const unsigned int rv0 = __shfl_xor(send0, 32);
            const unsigned int rv1 = __shfl_xor(send1, 32);
            const unsigned int own0 = h32 ? B0 : A0, own1 = h32 ? B1 : A1;
            P.u[0] = h32 ? rv0 : own0;
            P.u[1] = h32 ? rv1 : own1;
            P.u[2] = h32 ? own0 : rv0;
            P.u[3] = h32 ? own1 : rv1;
#endif
            const int swzr = (kc * 2 + h32) ^ (l5 & 7) ^ ((l5 >> 3) << 1);
            bf16x8 vf = *reinterpret_cast<const bf16x8*>(
                &Vt[cur + kh][l5 * 72 + swzr * 8]);
            o = MFMA32(vf, P.v, o);
        }

        // ---- stage next pair into other buffers; one barrier per iter ----
        if (t < 7) {
#pragma unroll
            for (int u = 0; u < 2; ++u) {
                short* kd = &Ks[(cur ^ 2) + u][sr * 36 + sc];
                *reinterpret_cast<short4*>(kd)     = *reinterpret_cast<short4*>(&kn[u]);
                *reinterpret_cast<short4*>(kd + 4) = *(reinterpret_cast<short4*>(&kn[u]) + 1);
                const short* vs = reinterpret_cast<const short*>(&vn[u]);
#pragma unroll
                for (int i = 0; i < 8; ++i) {
                    const int swz = srh ^ i ^ scg2;
                    Vt[(cur ^ 2) + u][(sc + i) * 72 + swz * 8 + srl] = vs[i];
                }
            }
            __syncthreads();
        }
    }

    // ---- k-half merge: plain add (fixed-max!).  kh=1 posts {l, o[16]} over
    //      retired K buffers 0,1 (iteration 7 reads buffers 2,3 only). ----
    float* scr = reinterpret_cast<float*>(&Ks[0][0]);   // 2304 floats needed <= 4608
    if (kh == 1) {
        float* myb = scr + qw * 1152 + lane * 18;
        myb[0] = lr;
#pragma unroll
        for (int r = 0; r < 16; ++r) myb[1 + r] = o[r];
    }
    __syncthreads();

    if (kh == 0) {
        const float* pb = scr + qw * 1152 + lane * 18;
        float lsum = lr + pb[0];
        lsum += __shfl_xor(lsum, 32);
        const float inv = 1.0f / lsum;
        short* dst = &AO[((size_t)(b * 1024 + q)) * 256 + h * 32];
#pragma unroll
        for (int rg = 0; rg < 4; ++rg) {
            short4 s4;
            s4.x = f2s((o[rg * 4 + 0] + pb[1 + rg * 4 + 0]) * inv);
            s4.y = f2s((o[rg * 4 + 1] + pb[1 + rg * 4 + 1]) * inv);
            s4.z = f2s((o[rg * 4 + 2] + pb[1 + rg * 4 + 2]) * inv);
            s4.w = f2s((o[rg * 4 + 3] + pb[1 + rg * 4 + 3]) * inv);
            *reinterpret_cast<short4*>(&dst[rg * 8 + h32 * 4]) = s4;
        }
    }
}

// ---------------------------------------------------------------------------
// Kernel C: output projection (verbatim, verified).
// ---------------------------------------------------------------------------
__global__ __launch_bounds__(256)
void out_gemm(const short* __restrict__ AO, const float* __restrict__ Wo,
              const float* __restrict__ bo, float* __restrict__ out)
{
    __shared__ short As[128 * 72];
    __shared__ short Bs[64 * 72];

    const int tid = threadIdx.x, lane = tid & 63, wid = tid >> 6;
    const int wr = wid >> 1, wcn = wid & 1;
    const int g = lane >> 4, li = lane & 15;
    const int m0 = blockIdx.x * 128, n0 = blockIdx.y * 64;

    f32x4 acc[4][2] = {};
    const int ar = tid >> 3, ac8 = (tid & 7) * 8;
    const int br = tid >> 4, bc4 = (tid & 15) * 4;

    for (int k0 = 0; k0 < 256; k0 += 64) {
        __syncthreads();
#pragma unroll
        for (int it = 0; it < 4; ++it) {
            int row = ar + it * 32;
            *reinterpret_cast<int4*>(&As[row * 72 + ac8]) =
                *reinterpret_cast<const int4*>(&AO[(m0 + row) * 256 + k0 + ac8]);
        }
#pragma unroll
        for (int it = 0; it < 4; ++it) {
            int row = br + it * 16;
            float4 v = *reinterpret_cast<const float4*>(&Wo[(n0 + row) * 256 + k0 + bc4]);
            short4 s4; s4.x = f2s(v.x); s4.y = f2s(v.y); s4.z = f2s(v.z); s4.w = f2s(v.w);
            *reinterpret_cast<short4*>(&Bs[row * 72 + bc4]) = s4;
        }
        __syncthreads();
#pragma unroll
        for (int ks = 0; ks < 2; ++ks) {
            const int kb = ks * 32 + g * 8;
            bf16x8 a[4], bb[2];
#pragma unroll
            for (int i = 0; i < 4; ++i)
                a[i] = *reinterpret_cast<const bf16x8*>(&As[(wr * 64 + i * 16 + li) * 72 + kb]);
#pragma unroll
            for (int j = 0; j < 2; ++j)
                bb[j] = *reinterpret_cast<const bf16x8*>(&Bs[(wcn * 32 + j * 16 + li) * 72 + kb]);
#pragma unroll
            for (int i = 0; i < 4; ++i)
#pragma unroll
                for (int j = 0; j < 2; ++j)
                    acc[i][j] = MFMA16(a[i], bb[j], acc[i][j]);
        }
    }
#pragma unroll
    for (int j = 0; j < 2; ++j) {
        const int col = n0 + wcn * 32 + j * 16 + li;
        const float bv_ = bo[col];
#pragma unroll
        for (int i = 0; i < 4; ++i)
#pragma unroll
            for (int r = 0; r < 4; ++r) {
                const int row = m0 + wr * 64 + i * 16 + g * 4 + r;
                out[row * 256 + col] = acc[i][j][r] + bv_;
            }
    }
}

extern "C" void kernel_launch(void* const* d_in, const int* in_sizes, int n_in,
                              void* d_out, int out_size, void* d_ws, size_t ws_size,
                              hipStream_t stream)
{
    const float* x  = (const float*)d_in[0];
    const int*   adj = (const int*)d_in[1];
    const float* Wq = (const float*)d_in[2];
    const float* bq = (const float*)d_in[3];
    const float* Wk = (const float*)d_in[4];
    const float* bk = (const float*)d_in[5];
    const float* Wv = (const float*)d_in[6];
    const float* bv = (const float*)d_in[7];
    const float* Wo = (const float*)d_in[8];
    const float* bo = (const float*)d_in[9];
    const float* ee = (const float*)d_in[10];
    float* out = (float*)d_out;

    // Workspace: Qb/Kb/Vb [64][1024][32] bf16 (4MB each), AO [8192][256] bf16 (4MB),
    // adjG [8][32][16][8][64] u32 (8MB)  -> 24MB total (known-good budget)
    short* Qb = (short*)d_ws;
    short* Kb = Qb + 2 * 1024 * 1024;
    short* Vb = Kb + 2 * 1024 * 1024;
    short* AO = Vb + 2 * 1024 * 1024;
    unsigned int* adjG = (unsigned int*)(AO + 2 * 1024 * 1024);

    qkv3_and_gather<<<1280, 256, 0, stream>>>(x, Wq, bq, Wk, bk, Wv, bv,
                                              Qb, Kb, Vb, adj, adjG);
    attn12<<<dim3(16, 64), 256, 0, stream>>>(Qb, Kb, Vb, adjG, ee, AO);
    out_gemm<<<dim3(64, 4), 256, 0, stream>>>(AO, Wo, bo, out);
}

// Round 20
// 51.245 us; speedup vs baseline: 1.0270x; 1.0270x over previous
//
#include <hip/hip_runtime.h>
#include <hip/hip_bf16.h>

typedef float f32x4 __attribute__((ext_vector_type(4)));
typedef float f32x16 __attribute__((ext_vector_type(16)));
typedef __bf16 bf16x8 __attribute__((ext_vector_type(8)));
typedef unsigned int uint2v __attribute__((ext_vector_type(2)));

#define MFMA16(a, b, c) __builtin_amdgcn_mfma_f32_16x16x32_bf16((a), (b), (c), 0, 0, 0)
#define MFMA32(a, b, c) __builtin_amdgcn_mfma_f32_32x32x16_bf16((a), (b), (c), 0, 0, 0)

static __device__ __forceinline__ short f2s(float f) {
    __hip_bfloat16 h = __float2bfloat16(f);
    return *reinterpret_cast<short*>(&h);
}
static __device__ __forceinline__ unsigned int cvtpk(float lo, float hi) {
    unsigned int r;
    asm("v_cvt_pk_bf16_f32 %0, %1, %2" : "=v"(r) : "v"(lo), "v"(hi));
    return r;
}
static __device__ __forceinline__ float exp2f_fast(float x) {
#if __has_builtin(__builtin_amdgcn_exp2f)
    return __builtin_amdgcn_exp2f(x);
#else
    return exp2f(x);
#endif
}

// ---------------------------------------------------------------------------
// Kernel A (fused front): blocks [0,256) = QKV projection with 3-matrix
// A-tile reuse; blocks [256,1280) = adj gather.  ONE change vs verified
// round 18: Q is written pre-scaled by c1 = log2(e)/sqrt(32), deleting the
// per-element multiply from attn's softmax hot loop (exact: same single
// bf16 rounding).
// ---------------------------------------------------------------------------
__global__ __launch_bounds__(256)
void qkv3_and_gather(const float* __restrict__ x,
                     const float* __restrict__ Wq, const float* __restrict__ bq,
                     const float* __restrict__ Wk, const float* __restrict__ bk,
                     const float* __restrict__ Wv, const float* __restrict__ bv,
                     short* __restrict__ Qb, short* __restrict__ Kb, short* __restrict__ Vb,
                     const int* __restrict__ adj, unsigned int* __restrict__ adjG)
{
    __shared__ short As[128 * 72];
    __shared__ short Bs[3][64 * 72];

    const int bx = blockIdx.x;
    const int tid = threadIdx.x;

    if (bx < 256) {
        const int lane = tid & 63;
        const int wid = tid >> 6;
        const int wr = wid >> 1, wc = wid & 1;
        const int g = lane >> 4, li = lane & 15;

        const int m0 = (bx & 63) * 128;
        const int wc0 = (bx >> 6) * 64;

        const float* Wm[3]  = { Wq, Wk, Wv };
        const float* bm[3]  = { bq, bk, bv };
        short*       Om[3]  = { Qb, Kb, Vb };

        f32x4 acc[3][4][2] = {};

        const int sr = tid >> 4;
        const int sc4 = (tid & 15) * 4;

        for (int k0 = 0; k0 < 256; k0 += 64) {
            __syncthreads();
#pragma unroll
            for (int it = 0; it < 8; ++it) {
                int row = sr + it * 16;
                float4 v = *reinterpret_cast<const float4*>(&x[(m0 + row) * 256 + k0 + sc4]);
                short4 s4;
                s4.x = f2s(v.x); s4.y = f2s(v.y); s4.z = f2s(v.z); s4.w = f2s(v.w);
                *reinterpret_cast<short4*>(&As[row * 72 + sc4]) = s4;
            }
#pragma unroll
            for (int mat = 0; mat < 3; ++mat) {
#pragma unroll
                for (int it = 0; it < 4; ++it) {
                    int row = sr + it * 16;
                    float4 v = *reinterpret_cast<const float4*>(
                        &Wm[mat][(wc0 + row) * 256 + k0 + sc4]);
                    short4 s4;
                    s4.x = f2s(v.x); s4.y = f2s(v.y); s4.z = f2s(v.z); s4.w = f2s(v.w);
                    *reinterpret_cast<short4*>(&Bs[mat][row * 72 + sc4]) = s4;
                }
            }
            __syncthreads();
#pragma unroll
            for (int ks = 0; ks < 2; ++ks) {
                const int kb = ks * 32 + g * 8;
                bf16x8 a[4];
#pragma unroll
                for (int i = 0; i < 4; ++i)
                    a[i] = *reinterpret_cast<const bf16x8*>(&As[(wr * 64 + i * 16 + li) * 72 + kb]);
#pragma unroll
                for (int mat = 0; mat < 3; ++mat) {
                    bf16x8 bfr[2];
#pragma unroll
                    for (int j = 0; j < 2; ++j)
                        bfr[j] = *reinterpret_cast<const bf16x8*>(
                            &Bs[mat][(wc * 32 + j * 16 + li) * 72 + kb]);
#pragma unroll
                    for (int i = 0; i < 4; ++i)
#pragma unroll
                        for (int j = 0; j < 2; ++j)
                            acc[mat][i][j] = MFMA16(a[i], bfr[j], acc[mat][i][j]);
                }
            }
        }

#pragma unroll
        for (int mat = 0; mat < 3; ++mat) {
            const float qscale = (mat == 0) ? 0.25503486f : 1.0f;  // c1 into Q
#pragma unroll
            for (int j = 0; j < 2; ++j) {
                const int colW = wc0 + wc * 32 + j * 16 + li;
                const int h = colW >> 5, d = colW & 31;
                const float bv_ = bm[mat][colW];
#pragma unroll
                for (int i = 0; i < 4; ++i) {
#pragma unroll
                    for (int r = 0; r < 4; ++r) {
                        const int row = m0 + wr * 64 + i * 16 + g * 4 + r;
                        const int bb = row >> 10, nq = row & 1023;
                        Om[mat][((bb * 8 + h) * 1024 + nq) * 32 + d] =
                            f2s((acc[mat][i][j][r] + bv_) * qscale);
                    }
                }
            }
        }
    } else {
        const int gx = bx - 256;               // 0..1023
        const int qt = gx & 31;
        const int b  = (gx >> 5) & 7;
        const int j0 = (gx >> 8) * 8;

        const int4* base = reinterpret_cast<const int4*>(
            adj + ((size_t)(b * 1024 + qt * 32)) * 1024);
        unsigned int* outT = adjG + ((size_t)(b * 32 + qt)) * 16 * 512;

        const int t = tid >> 4;
        const int i = (tid >> 1) & 7;
        const int laneb = 32 * (tid & 1);

#pragma unroll
        for (int jj = 0; jj < 8; ++jj) {
            const int j = j0 + jj;
            const int4 c = base[j * 256 + tid];
            const unsigned int packed =
                (unsigned)c.x | ((unsigned)c.y << 8) | ((unsigned)c.z << 16) | ((unsigned)c.w << 24);
            outT[t * 512 + i * 64 + (j + laneb)] = packed;
        }
    }
}

// ---------------------------------------------------------------------------
// Kernel B: edge-biased flash attention — round-19 attn12 (verified) with:
// (1) Q pre-scaled by c1 -> exp2 arg is the raw MFMA output (one mul fewer
//     per element); (2) pairwise lsum accumulation (8-deep chain, not 32).
// ---------------------------------------------------------------------------
__global__ __launch_bounds__(256, 4)
void attn12(const short* __restrict__ Qb, const short* __restrict__ Kb,
            const short* __restrict__ Vb, const unsigned int* __restrict__ adjG,
            const float* __restrict__ edge_emb, short* __restrict__ AO)
{
    __shared__ __align__(16) short Ks[4][64 * 36];   // [buf][row][d]
    __shared__ __align__(16) short Vt[4][32 * 72];   // [buf][d][krow] swizzled
    __shared__ float Etab[8];

    const int tid = threadIdx.x, lane = tid & 63, wid = tid >> 6;
    const int l5 = lane & 31, h32 = lane >> 5;
    const int qw = wid & 1, kh = wid >> 1;

    // bijective chunked XCD swizzle (1024 blocks = 8 XCD x 128)
    const int orig = blockIdx.x + blockIdx.y * 16;
    const int flat = (orig & 7) * 128 + (orig >> 3);
    const int qb = flat & 15, bh = flat >> 4;
    const int b = bh >> 3, h = bh & 7;
    const int qt = qb * 2 + qw;          // wave's q-tile (0..31)
    const int q  = qt * 32 + l5;

    const short* Qh = Qb + bh * (1024 * 32);
    const short* Kh = Kb + bh * (1024 * 32);
    const short* Vh = Vb + bh * (1024 * 32);
    const unsigned int* adjT = adjG + ((size_t)(b * 32 + qt)) * 16 * 512;

    if (tid < 5) Etab[tid] = __expf(edge_emb[tid * 8 + h]);

    // Q fragments (B-operand, pre-scaled by c1): col=q=l5, k(d)=c*16+h32*8+j
    const bf16x8 qf0 = *reinterpret_cast<const bf16x8*>(&Qh[q * 32 + h32 * 8]);
    const bf16x8 qf1 = *reinterpret_cast<const bf16x8*>(&Qh[q * 32 + 16 + h32 * 8]);

    const f32x16 zero16 = {};

    f32x16 o = {};
    float lr = 0.f;

    // staging map: thread -> (k-row sr = tid>>2, 16B chunk sc = (tid&3)*8)
    const int sr = tid >> 2;
    const int sc = (tid & 3) * 8;
    const int srh = sr >> 3, srl = sr & 7;     // V-swizzle components
    const int scg2 = (sc >> 3) << 1;

    // prologue: stage tile 0 (half 0) and tile 8 (half 1) into buffers 0,1
#pragma unroll
    for (int u = 0; u < 2; ++u) {
        const int row = u * 512 + sr;
        int4 kr = *reinterpret_cast<const int4*>(&Kh[row * 32 + sc]);
        int4 vr = *reinterpret_cast<const int4*>(&Vh[row * 32 + sc]);
        short* kd = &Ks[u][sr * 36 + sc];
        *reinterpret_cast<short4*>(kd)     = *reinterpret_cast<short4*>(&kr);
        *reinterpret_cast<short4*>(kd + 4) = *(reinterpret_cast<short4*>(&kr) + 1);
        const short* vs = reinterpret_cast<const short*>(&vr);
#pragma unroll
        for (int i = 0; i < 8; ++i) {
            const int swz = srh ^ i ^ scg2;
            Vt[u][(sc + i) * 72 + swz * 8 + srl] = vs[i];
        }
    }
    __syncthreads();

    for (int t = 0; t < 8; ++t) {
        const int cur = (t & 1) * 2;
        const int tt = kh * 8 + t;           // this wave's compute tile

        // ---- adj loads for this wave's tile ----
        unsigned int a4[8];
#pragma unroll
        for (int i = 0; i < 8; ++i)
            a4[i] = adjT[tt * 512 + i * 64 + lane];

        // ---- issue next-pair K/V global loads (both halves) ----
        int4 kn[2], vn[2];
        if (t < 7) {
#pragma unroll
            for (int u = 0; u < 2; ++u) {
                const int row = u * 512 + (t + 1) * 64 + sr;
                kn[u] = *reinterpret_cast<const int4*>(&Kh[row * 32 + sc]);
                vn[u] = *reinterpret_cast<const int4*>(&Vh[row * 32 + sc]);
            }
        }

        // ---- QK^T from this wave's buffer ----
        f32x16 s[2];
        {
            const short* KsC = &Ks[cur + kh][0];
#pragma unroll
            for (int ks = 0; ks < 2; ++ks) {
                union { short4 h4[2]; bf16x8 v; } kfa, kfb;
                const int rowb = (ks * 32 + l5) * 36;
                kfa.h4[0] = *reinterpret_cast<const short4*>(&KsC[rowb + h32 * 8]);
                kfa.h4[1] = *reinterpret_cast<const short4*>(&KsC[rowb + h32 * 8 + 4]);
                kfb.h4[0] = *reinterpret_cast<const short4*>(&KsC[rowb + 16 + h32 * 8]);
                kfb.h4[1] = *reinterpret_cast<const short4*>(&KsC[rowb + 16 + h32 * 8 + 4]);
                s[ks] = MFMA32(kfa.v, qf0, zero16);
                s[ks] = MFMA32(kfb.v, qf1, s[ks]);
            }
        }

        // ---- fixed-max softmax: p = exp2(s) * E[adj]; pack bf16 ----
        unsigned int pw[2][8];
#pragma unroll
        for (int ks = 0; ks < 2; ++ks) {
#pragma unroll
            for (int rg = 0; rg < 4; ++rg) {
                const unsigned int aw4 = a4[ks * 4 + rg] << 2;
                float pv[4];
#pragma unroll
                for (int j = 0; j < 4; ++j) {
                    const float Ev = *reinterpret_cast<const float*>(
                        reinterpret_cast<const char*>(&Etab[0]) +
                        ((aw4 >> (8 * j)) & 0x3FCu));
                    const float pe = exp2f_fast(s[ks][rg * 4 + j]);
                    pv[j] = pe * Ev;
                }
                lr += (pv[0] + pv[1]) + (pv[2] + pv[3]);
                pw[ks][rg * 2 + 0] = cvtpk(pv[0], pv[1]);
                pw[ks][rg * 2 + 1] = cvtpk(pv[2], pv[3]);
            }
        }

        // ---- PV: O^T += V^T . P^T ----
#pragma unroll
        for (int kc = 0; kc < 4; ++kc) {
            const int ks = kc >> 1, half = kc & 1;
            const unsigned int A0 = pw[ks][4 * half + 0], A1 = pw[ks][4 * half + 1];
            const unsigned int B0 = pw[ks][4 * half + 2], B1 = pw[ks][4 * half + 3];
            union { unsigned int u[4]; bf16x8 v; } P;
#if __has_builtin(__builtin_amdgcn_permlane32_swap)
            uint2v r02 = __builtin_amdgcn_permlane32_swap(A0, B0, false, false);
            uint2v r13 = __builtin_amdgcn_permlane32_swap(A1, B1, false, false);
            P.u[0] = r02.x; P.u[1] = r13.x;
            P.u[2] = r02.y; P.u[3] = r13.y;
#else
            const unsigned int send0 = h32 ? A0 : B0, send1 = h32 ? A1 : B1;
            const unsigned int rv0 = __shfl_xor(send0, 32);
            const unsigned int rv1 = __shfl_xor(send1, 32);
            const unsigned int own0 = h32 ? B0 : A0, own1 = h32 ? B1 : A1;
            P.u[0] = h32 ? rv0 : own0;
            P.u[1] = h32 ? rv1 : own1;
            P.u[2] = h32 ? own0 : rv0;
            P.u[3] = h32 ? own1 : rv1;
#endif
            const int swzr = (kc * 2 + h32) ^ (l5 & 7) ^ ((l5 >> 3) << 1);
            bf16x8 vf = *reinterpret_cast<const bf16x8*>(
                &Vt[cur + kh][l5 * 72 + swzr * 8]);
            o = MFMA32(vf, P.v, o);
        }

        // ---- stage next pair into other buffers; one barrier per iter ----
        if (t < 7) {
#pragma unroll
            for (int u = 0; u < 2; ++u) {
                short* kd = &Ks[(cur ^ 2) + u][sr * 36 + sc];
                *reinterpret_cast<short4*>(kd)     = *reinterpret_cast<short4*>(&kn[u]);
                *reinterpret_cast<short4*>(kd + 4) = *(reinterpret_cast<short4*>(&kn[u]) + 1);
                const short* vs = reinterpret_cast<const short*>(&vn[u]);
#pragma unroll
                for (int i = 0; i < 8; ++i) {
                    const int swz = srh ^ i ^ scg2;
                    Vt[(cur ^ 2) + u][(sc + i) * 72 + swz * 8 + srl] = vs[i];
                }
            }
            __syncthreads();
        }
    }

    // ---- k-half merge: plain add (fixed-max!).  kh=1 posts {l, o[16]} over
    //      retired K buffers 0,1 (iteration 7 reads buffers 2,3 only). ----
    float* scr = reinterpret_cast<float*>(&Ks[0][0]);   // 2304 floats <= 4608
    if (kh == 1) {
        float* myb = scr + qw * 1152 + lane * 18;
        myb[0] = lr;
#pragma unroll
        for (int r = 0; r < 16; ++r) myb[1 + r] = o[r];
    }
    __syncthreads();

    if (kh == 0) {
        const float* pb = scr + qw * 1152 + lane * 18;
        float lsum = lr + pb[0];
        lsum += __shfl_xor(lsum, 32);
        const float inv = 1.0f / lsum;
        short* dst = &AO[((size_t)(b * 1024 + q)) * 256 + h * 32];
#pragma unroll
        for (int rg = 0; rg < 4; ++rg) {
            short4 s4;
            s4.x = f2s((o[rg * 4 + 0] + pb[1 + rg * 4 + 0]) * inv);
            s4.y = f2s((o[rg * 4 + 1] + pb[1 + rg * 4 + 1]) * inv);
            s4.z = f2s((o[rg * 4 + 2] + pb[1 + rg * 4 + 2]) * inv);
            s4.w = f2s((o[rg * 4 + 3] + pb[1 + rg * 4 + 3]) * inv);
            *reinterpret_cast<short4*>(&dst[rg * 8 + h32 * 4]) = s4;
        }
    }
}

// ---------------------------------------------------------------------------
// Kernel C: output projection — 128x32 tiles, grid (64,8) = 512 blocks
// (2 blocks/CU): A-staging per block UNCHANGED vs the verified 128x64
// version (round-17's 64x64 failure doubled it); only B is split.  Same
// verified MFMA16 fragment paths; each wave computes 32x32 via 2x2 frags.
// ---------------------------------------------------------------------------
__global__ __launch_bounds__(256)
void out_gemm32(const short* __restrict__ AO, const float* __restrict__ Wo,
                const float* __restrict__ bo, float* __restrict__ out)
{
    __shared__ short As[128 * 72];
    __shared__ short Bs[32 * 72];

    const int tid = threadIdx.x, lane = tid & 63, wid = tid >> 6;
    const int g = lane >> 4, li = lane & 15;
    const int m0 = blockIdx.x * 128, n0 = blockIdx.y * 32;

    f32x4 acc[2][2] = {};
    const int ar = tid >> 3, ac8 = (tid & 7) * 8;   // A: rows ar+32*it
    const int br = tid >> 3, bc8 = (tid & 7) * 8;   // B: 32 rows, 8 f32/thread

    for (int k0 = 0; k0 < 256; k0 += 64) {
        __syncthreads();
#pragma unroll
        for (int it = 0; it < 4; ++it) {
            int row = ar + it * 32;
            *reinterpret_cast<int4*>(&As[row * 72 + ac8]) =
                *reinterpret_cast<const int4*>(&AO[(m0 + row) * 256 + k0 + ac8]);
        }
        {
            float4 v0 = *reinterpret_cast<const float4*>(&Wo[(n0 + br) * 256 + k0 + bc8]);
            float4 v1 = *reinterpret_cast<const float4*>(&Wo[(n0 + br) * 256 + k0 + bc8 + 4]);
            short4 s0, s1;
            s0.x = f2s(v0.x); s0.y = f2s(v0.y); s0.z = f2s(v0.z); s0.w = f2s(v0.w);
            s1.x = f2s(v1.x); s1.y = f2s(v1.y); s1.z = f2s(v1.z); s1.w = f2s(v1.w);
            *reinterpret_cast<short4*>(&Bs[br * 72 + bc8])     = s0;
            *reinterpret_cast<short4*>(&Bs[br * 72 + bc8 + 4]) = s1;
        }
        __syncthreads();
#pragma unroll
        for (int ks = 0; ks < 2; ++ks) {
            const int kb = ks * 32 + g * 8;
            bf16x8 a[2], bb[2];
#pragma unroll
            for (int i = 0; i < 2; ++i)
                a[i] = *reinterpret_cast<const bf16x8*>(&As[(wid * 32 + i * 16 + li) * 72 + kb]);
#pragma unroll
            for (int j = 0; j < 2; ++j)
                bb[j] = *reinterpret_cast<const bf16x8*>(&Bs[(j * 16 + li) * 72 + kb]);
#pragma unroll
            for (int i = 0; i < 2; ++i)
#pragma unroll
                for (int j = 0; j < 2; ++j)
                    acc[i][j] = MFMA16(a[i], bb[j], acc[i][j]);
        }
    }
#pragma unroll
    for (int j = 0; j < 2; ++j) {
        const int col = n0 + j * 16 + li;
        const float bv_ = bo[col];
#pragma unroll
        for (int i = 0; i < 2; ++i)
#pragma unroll
            for (int r = 0; r < 4; ++r) {
                const int row = m0 + wid * 32 + i * 16 + g * 4 + r;
                out[row * 256 + col] = acc[i][j][r] + bv_;
            }
    }
}

extern "C" void kernel_launch(void* const* d_in, const int* in_sizes, int n_in,
                              void* d_out, int out_size, void* d_ws, size_t ws_size,
                              hipStream_t stream)
{
    const float* x  = (const float*)d_in[0];
    const int*   adj = (const int*)d_in[1];
    const float* Wq = (const float*)d_in[2];
    const float* bq = (const float*)d_in[3];
    const float* Wk = (const float*)d_in[4];
    const float* bk = (const float*)d_in[5];
    const float* Wv = (const float*)d_in[6];
    const float* bv = (const float*)d_in[7];
    const float* Wo = (const float*)d_in[8];
    const float* bo = (const float*)d_in[9];
    const float* ee = (const float*)d_in[10];
    float* out = (float*)d_out;

    // Workspace: Qb/Kb/Vb [64][1024][32] bf16 (4MB each), AO [8192][256] bf16 (4MB),
    // adjG [8][32][16][8][64] u32 (8MB)  -> 24MB total (known-good budget)
    short* Qb = (short*)d_ws;
    short* Kb = Qb + 2 * 1024 * 1024;
    short* Vb = Kb + 2 * 1024 * 1024;
    short* AO = Vb + 2 * 1024 * 1024;
    unsigned int* adjG = (unsigned int*)(AO + 2 * 1024 * 1024);

    qkv3_and_gather<<<1280, 256, 0, stream>>>(x, Wq, bq, Wk, bk, Wv, bv,
                                              Qb, Kb, Vb, adj, adjG);
    attn12<<<dim3(16, 64), 256, 0, stream>>>(Qb, Kb, Vb, adjG, ee, AO);
    out_gemm32<<<dim3(64, 8), 256, 0, stream>>>(AO, Wo, bo, out);
}